// Round 5
// baseline (513.451 us; speedup 1.0000x reference)
//
#include <hip/hip_runtime.h>
#include <hip/hip_fp16.h>
#include <cstddef>

// AffinityPropagate: per-pixel normalized 3x3 stencil, 24 steps.
// R10: attack LDS INSTRUCTION-ISSUE overhead (R6's 38 wave-wide b32 ops/step
// run at 44 B/cy effective vs 128 B/cy LDS peak; modeled ~5.3K of the 7.9K
// cy/step wall). Thread unit = 4 cols x 2 rows (8 px), staged grid shifted
// +1 col so outputs sit at staged col % 4 == 2: window = 4 rows x 8 dwords
// read as 8x ds_read_b128 (16B aligned), outputs = 2 aligned float2 per row
// (ds_write2_b64). LDS insts/wave-step 38 -> ~10. Bank math per 16-lane
// phase: b128 reads = 64 contiguous dwords = 2/bank (free, m136); b64
// writes stride-4-dword = 16 banks 2-way (free). R8's regression was
// stride-2 col units (real conflicts, +5.4M cy) -- 4-col units avoid that.
// Weights stay packed half2 (R9 proved compiler emits v_fma_mix).
// launch_bounds(512,6) caps VGPR at 85 -> keeps 3 blocks/CU.
//
// Tap order: w0=NW w1=N w2=NE w3=W [center] w4=E w5=SW w6=S w7=SE
//
// Coords: staged row r in 0..65 <-> gy = oy-13+r (unshifted). Staged col
// c in 0..67 <-> gx = ox-14+c (shifted +1; cols 0 and 67 are alignment pads,
// loaded but never used in any FMA). Weight px (wy,wx) <-> staged
// (wy+1, wx+2). Valid staged ring after step s: rows [s,65-s] (old coords),
// cols [s+1,66-s] (shifted). Writes each step: staged rows 1..64, cols
// 2..65. After 12 steps output tile = staged rows 13..52, cols 14..53.
// Out-of-image px have all-zero weights -> stay exactly 0 = zero padding.
// Stale/garbage cells are finite (0-init fB, finite weights) and provably
// never read by any in-ring output (same ring argument as R5-R9).

#define HIMG 480
#define WIMG 640
#define HW   (HIMG * WIMG)
#define BN   8

#define TILE   40
#define TSTEPS 12
#define IH     13                // staged halo (rows); col halo is 13 at c=1
#define WHL    12                // weight halo
#define ROWS   66                // staged rows
#define PITCH  68                // LDS row pitch = staged cols (2 pad cols)
#define NT     512

#define WS_FRAME_B  ((size_t)BN * HW * 4)            // 9,830,400
#define WS_WA_B     ((size_t)BN * HW * 16)           // 39,321,600
#define WS_WC_B     ((size_t)BN * HW * 4)            // 9,830,400
#define WS_NEED     (WS_FRAME_B + WS_WA_B + WS_WC_B) // 58,982,400

// MODE: 0 = normalize in-kernel + store interior weights to wA/wC
//       1 = load packed weights from wA/wC
//       2 = normalize in-kernel, no store (fallback when ws too small)
template <int MODE>
__global__ __launch_bounds__(NT, 6) void affprop12(
    const float* __restrict__ aff,
    __half2* __restrict__ wA,
    float* __restrict__ wC,
    const float* __restrict__ src,
    float* __restrict__ dst)
{
    __shared__ float fA[ROWS * PITCH];
    __shared__ float fB[ROWS * PITCH];

    const int tid = threadIdx.x;
    const int ox  = blockIdx.x * TILE;
    const int oy  = blockIdx.y * TILE;
    const int b   = blockIdx.z;

    const float* __restrict__ sb = src + (size_t)b * HW;
    float*       __restrict__ db = dst + (size_t)b * HW;

    // ---- stage rows [oy-13,oy+53) x cols [ox-14,ox+54), 0 outside image
    for (int i = tid; i < ROWS * PITCH; i += NT) {
        int r  = i / PITCH;
        int c  = i - r * PITCH;
        int gy = oy - IH + r;
        int gx = ox - IH - 1 + c;
        float v = 0.f;
        if ((unsigned)gy < (unsigned)HIMG && (unsigned)gx < (unsigned)WIMG)
            v = sb[gy * WIMG + gx];
        fA[i] = v;
    }
    // ---- zero-fill buffer B (deterministic stale rings); 4488/4 = 1122
    for (int i = tid; i < ROWS * PITCH / 4; i += NT)
        *(float4*)&fB[4 * i] = make_float4(0.f, 0.f, 0.f, 0.f);

    // ---- per-thread: 4 weight cols x 2 weight rows
    const int cu = tid & 15;          // col unit: weight cols 4cu..4cu+3
    const int R  = tid >> 4;          // row pair 0..31: weight rows 2R, 2R+1
    const int w  = tid >> 6;          // wave id: weight rows 8w..8w+7

    __half2 wv[2][4][4];  // [row r][col k][tap pair (01)(23)(45)(67)]
    float   wcc[2][4];    // center weights (f32)

    #pragma unroll
    for (int r = 0; r < 2; ++r) {
        #pragma unroll
        for (int k = 0; k < 4; ++k) {
            const int gy = oy - WHL + 2 * R + r;
            const int gx = ox - WHL + 4 * cu + k;
            const bool in = (unsigned)gy < (unsigned)HIMG && (unsigned)gx < (unsigned)WIMG;
            const size_t idx = (size_t)b * HW + (size_t)gy * WIMG + gx;

            if (MODE == 1) {
                if (in) {
                    union { float4 f4; __half2 h[4]; } u;
                    u.f4 = *(const float4*)(wA + 4 * idx);
                    wv[r][k][0] = u.h[0]; wv[r][k][1] = u.h[1];
                    wv[r][k][2] = u.h[2]; wv[r][k][3] = u.h[3];
                    wcc[r][k] = wC[idx];
                } else {
                    __half2 z = __floats2half2_rn(0.f, 0.f);
                    wv[r][k][0] = z; wv[r][k][1] = z;
                    wv[r][k][2] = z; wv[r][k][3] = z;
                    wcc[r][k] = 0.f;
                }
            } else {
                float wt[8];
                float s = 0.f;
                if (in) {
                    const float* ap = aff + (size_t)b * 8 * HW + (size_t)gy * WIMG + gx;
                    #pragma unroll
                    for (int t = 0; t < 8; ++t) { wt[t] = ap[(size_t)t * HW]; s += fabsf(wt[t]); }
                } else {
                    #pragma unroll
                    for (int t = 0; t < 8; ++t) wt[t] = 0.f;
                    s = 1.f;
                }
                float rr  = in ? 1.0f / s : 0.f;
                float acc = 0.f;
                #pragma unroll
                for (int t = 0; t < 8; ++t) { wt[t] *= rr; acc += wt[t]; }

                union { float4 f4; __half2 h[4]; } u;
                u.h[0] = __floats2half2_rn(wt[0], wt[1]);
                u.h[1] = __floats2half2_rn(wt[2], wt[3]);
                u.h[2] = __floats2half2_rn(wt[4], wt[5]);
                u.h[3] = __floats2half2_rn(wt[6], wt[7]);
                wv[r][k][0] = u.h[0]; wv[r][k][1] = u.h[1];
                wv[r][k][2] = u.h[2]; wv[r][k][3] = u.h[3];
                wcc[r][k] = in ? 1.0f - acc : 0.f;

                if (MODE == 0) {
                    // store interior weights for launch 2 (each image px
                    // interior to exactly one block; rows/cols unique/thread)
                    if ((unsigned)(gy - oy) < (unsigned)TILE &&
                        (unsigned)(gx - ox) < (unsigned)TILE) {
                        *(float4*)(wA + 4 * idx) = u.f4;
                        wC[idx] = wcc[r][k];
                    }
                }
            }
        }
    }
    __syncthreads();

    // ---- 12 fused steps; 4x8 window via 8x ds_read_b128, aligned b64 writes
    const float* fin = fA;
    float*       fo  = fB;

    #pragma unroll 1
    for (int s = 0; s < TSTEPS; ++s) {
        // wave-uniform liveness: wave w writes staged rows 8w+1..8w+8; row
        // ring needed after step s is [s+1, 64-s]
        const bool live = (8 * w + 8 >= s + 1) && (8 * w + 1 <= 64 - s);
        if (live) {
            // window staged rows 2R..2R+3, staged dword cols 4cu..4cu+7
            const float* bp = fin + (2 * R) * PITCH + 4 * cu;
            float4 A0 = *(const float4*)(bp);
            float4 A1 = *(const float4*)(bp + 4);
            float4 B0 = *(const float4*)(bp + PITCH);
            float4 B1 = *(const float4*)(bp + PITCH + 4);
            float4 C0 = *(const float4*)(bp + 2 * PITCH);
            float4 C1 = *(const float4*)(bp + 2 * PITCH + 4);
            float4 D0 = *(const float4*)(bp + 3 * PITCH);
            float4 D1 = *(const float4*)(bp + 3 * PITCH + 4);
            float a[8] = {A0.x, A0.y, A0.z, A0.w, A1.x, A1.y, A1.z, A1.w};
            float bb[8] = {B0.x, B0.y, B0.z, B0.w, B1.x, B1.y, B1.z, B1.w};
            float cc[8] = {C0.x, C0.y, C0.z, C0.w, C1.x, C1.y, C1.z, C1.w};
            float dd[8] = {D0.x, D0.y, D0.z, D0.w, D1.x, D1.y, D1.z, D1.w};

            // outputs: weight rows 2R,2R+1 = staged rows 2R+1,2R+2;
            // weight col 4cu+k = staged col 4cu+2+k; window idx k+1..k+3
            float o0[4], o1[4];
            #pragma unroll
            for (int k = 0; k < 4; ++k) {
                o0[k] = wcc[0][k] * bb[k + 2]
                    + __low2float (wv[0][k][0]) * a [k + 1]   // NW
                    + __high2float(wv[0][k][0]) * a [k + 2]   // N
                    + __low2float (wv[0][k][1]) * a [k + 3]   // NE
                    + __high2float(wv[0][k][1]) * bb[k + 1]   // W
                    + __low2float (wv[0][k][2]) * bb[k + 3]   // E
                    + __high2float(wv[0][k][2]) * cc[k + 1]   // SW
                    + __low2float (wv[0][k][3]) * cc[k + 2]   // S
                    + __high2float(wv[0][k][3]) * cc[k + 3];  // SE
                o1[k] = wcc[1][k] * cc[k + 2]
                    + __low2float (wv[1][k][0]) * bb[k + 1]
                    + __high2float(wv[1][k][0]) * bb[k + 2]
                    + __low2float (wv[1][k][1]) * bb[k + 3]
                    + __high2float(wv[1][k][1]) * cc[k + 1]
                    + __low2float (wv[1][k][2]) * cc[k + 3]
                    + __high2float(wv[1][k][2]) * dd[k + 1]
                    + __low2float (wv[1][k][3]) * dd[k + 2]
                    + __high2float(wv[1][k][3]) * dd[k + 3];
            }
            float* wp = fo + (2 * R + 1) * PITCH + 4 * cu + 2;   // 8B aligned
            *(float2*)(wp)             = make_float2(o0[0], o0[1]);
            *(float2*)(wp + 2)         = make_float2(o0[2], o0[3]);
            *(float2*)(wp + PITCH)     = make_float2(o1[0], o1[1]);
            *(float2*)(wp + PITCH + 2) = make_float2(o1[2], o1[3]);
        }
        __syncthreads();
        const float* t = fin; fin = fo; fo = (float*)t;
    }

    // ---- store 40x40 tile (fin == fA after 12 steps);
    //      gy = oy+r -> staged row 13+r; gx = ox+c -> staged col 14+c
    for (int i = tid; i < TILE * (TILE / 4); i += NT) {
        int r  = i / (TILE / 4);
        int c4 = (i - r * (TILE / 4)) * 4;
        const float* p = fin + (IH + r) * PITCH + (IH + 1) + c4;
        float4 v = make_float4(p[0], p[1], p[2], p[3]);
        *(float4*)&db[(size_t)(oy + r) * WIMG + ox + c4] = v;
    }
}

extern "C" void kernel_launch(void* const* d_in, const int* in_sizes, int n_in,
                              void* d_out, int out_size, void* d_ws, size_t ws_size,
                              hipStream_t stream)
{
    const float* aff  = (const float*)d_in[0];
    const float* feat = (const float*)d_in[1];
    float* out = (float*)d_out;

    char* ws = (char*)d_ws;
    float*   wsFrame = (float*)ws;
    __half2* wA      = (__half2*)(ws + WS_FRAME_B);
    float*   wC      = (float*)(ws + WS_FRAME_B + WS_WA_B);

    dim3 blk(NT, 1, 1);
    dim3 grd(WIMG / TILE, HIMG / TILE, BN);   // 16 x 12 x 8 = 1536 blocks

    if (ws_size >= WS_NEED) {
        affprop12<0><<<grd, blk, 0, stream>>>(aff, wA, wC, feat, wsFrame);
        affprop12<1><<<grd, blk, 0, stream>>>(aff, wA, wC, wsFrame, out);
    } else {
        affprop12<2><<<grd, blk, 0, stream>>>(aff, nullptr, nullptr, feat, wsFrame);
        affprop12<2><<<grd, blk, 0, stream>>>(aff, nullptr, nullptr, wsFrame, out);
    }
}

// Round 6
// 295.111 us; speedup vs baseline: 1.7399x; 1.7399x over previous
//
#include <hip/hip_runtime.h>
#include <hip/hip_fp16.h>
#include <cstddef>

// AffinityPropagate: per-pixel normalized 3x3 stencil, 24 steps.
// R11 = R10 structure with the spill bug fixed: launch_bounds(512,4).
// R10's launch_bounds(512,6) capped VGPR at 40 < the ~72-reg live weight set
// -> full scratch spill (FETCH 100->563MB, VALUBusy 10%, 284us). This is the
// valid test of the LDS-instruction-issue theory: thread unit = 4 cols x
// 2 rows, window = 4 rows x 8 dwords read as 8x ds_read_b128 (16B aligned
// via +1 col grid shift), outputs = 2 aligned float2 per row. LDS insts per
// wave-step: 38 (R6, all b32) -> 12. Bank math per phase: b128 reads = 16
// lanes x 4 dwords = 64 contiguous dwords = 2/bank free; b64 writes =
// stride-4 dwords, ~4-way across a 32-lane phase (1.58x on 4 insts, ok).
// Weights stay packed half2 (R9 proved compiler emits v_fma_mix).
//
// Tap order: w0=NW w1=N w2=NE w3=W [center] w4=E w5=SW w6=S w7=SE
//
// Coords: staged row r in 0..65 <-> gy = oy-13+r. Staged col c in 0..67 <->
// gx = ox-14+c (shifted +1; cols 0 and 67 are alignment pads, loaded but
// never used in any FMA). Weight px (wy,wx) <-> staged (wy+1, wx+2).
// Valid staged ring after step s: rows [s,65-s], cols [s+1,66-s]. Writes
// each step: staged rows 1..64, cols 2..65. After 12 steps output tile =
// staged rows 13..52, cols 14..53. Out-of-image px have all-zero weights ->
// stay exactly 0 = zero padding. Stale/garbage cells are finite (0-init fB)
// and never read by any in-ring output (same ring argument as R5-R10).

#define HIMG 480
#define WIMG 640
#define HW   (HIMG * WIMG)
#define BN   8

#define TILE   40
#define TSTEPS 12
#define IH     13                // staged halo (rows); col halo is 13 at c=1
#define WHL    12                // weight halo
#define ROWS   66                // staged rows
#define PITCH  68                // LDS row pitch = staged cols (2 pad cols)
#define NT     512

#define WS_FRAME_B  ((size_t)BN * HW * 4)            // 9,830,400
#define WS_WA_B     ((size_t)BN * HW * 16)           // 39,321,600
#define WS_WC_B     ((size_t)BN * HW * 4)            // 9,830,400
#define WS_NEED     (WS_FRAME_B + WS_WA_B + WS_WC_B) // 58,982,400

// MODE: 0 = normalize in-kernel + store interior weights to wA/wC
//       1 = load packed weights from wA/wC
//       2 = normalize in-kernel, no store (fallback when ws too small)
template <int MODE>
__global__ __launch_bounds__(NT, 4) void affprop12(
    const float* __restrict__ aff,
    __half2* __restrict__ wA,
    float* __restrict__ wC,
    const float* __restrict__ src,
    float* __restrict__ dst)
{
    __shared__ float fA[ROWS * PITCH];
    __shared__ float fB[ROWS * PITCH];

    const int tid = threadIdx.x;
    const int ox  = blockIdx.x * TILE;
    const int oy  = blockIdx.y * TILE;
    const int b   = blockIdx.z;

    const float* __restrict__ sb = src + (size_t)b * HW;
    float*       __restrict__ db = dst + (size_t)b * HW;

    // ---- stage rows [oy-13,oy+53) x cols [ox-14,ox+54), 0 outside image
    for (int i = tid; i < ROWS * PITCH; i += NT) {
        int r  = i / PITCH;
        int c  = i - r * PITCH;
        int gy = oy - IH + r;
        int gx = ox - IH - 1 + c;
        float v = 0.f;
        if ((unsigned)gy < (unsigned)HIMG && (unsigned)gx < (unsigned)WIMG)
            v = sb[gy * WIMG + gx];
        fA[i] = v;
    }
    // ---- zero-fill buffer B (deterministic stale rings)
    for (int i = tid; i < ROWS * PITCH / 4; i += NT)
        *(float4*)&fB[4 * i] = make_float4(0.f, 0.f, 0.f, 0.f);

    // ---- per-thread: 4 weight cols x 2 weight rows
    const int cu = tid & 15;          // col unit: weight cols 4cu..4cu+3
    const int R  = tid >> 4;          // row pair 0..31: weight rows 2R, 2R+1
    const int w  = tid >> 6;          // wave id: weight rows 8w..8w+7

    __half2 wv[2][4][4];  // [row r][col k][tap pair (01)(23)(45)(67)]
    float   wcc[2][4];    // center weights (f32)

    #pragma unroll
    for (int r = 0; r < 2; ++r) {
        #pragma unroll
        for (int k = 0; k < 4; ++k) {
            const int gy = oy - WHL + 2 * R + r;
            const int gx = ox - WHL + 4 * cu + k;
            const bool in = (unsigned)gy < (unsigned)HIMG && (unsigned)gx < (unsigned)WIMG;
            const size_t idx = (size_t)b * HW + (size_t)gy * WIMG + gx;

            if (MODE == 1) {
                if (in) {
                    union { float4 f4; __half2 h[4]; } u;
                    u.f4 = *(const float4*)(wA + 4 * idx);
                    wv[r][k][0] = u.h[0]; wv[r][k][1] = u.h[1];
                    wv[r][k][2] = u.h[2]; wv[r][k][3] = u.h[3];
                    wcc[r][k] = wC[idx];
                } else {
                    __half2 z = __floats2half2_rn(0.f, 0.f);
                    wv[r][k][0] = z; wv[r][k][1] = z;
                    wv[r][k][2] = z; wv[r][k][3] = z;
                    wcc[r][k] = 0.f;
                }
            } else {
                float wt[8];
                float s = 0.f;
                if (in) {
                    const float* ap = aff + (size_t)b * 8 * HW + (size_t)gy * WIMG + gx;
                    #pragma unroll
                    for (int t = 0; t < 8; ++t) { wt[t] = ap[(size_t)t * HW]; s += fabsf(wt[t]); }
                } else {
                    #pragma unroll
                    for (int t = 0; t < 8; ++t) wt[t] = 0.f;
                    s = 1.f;
                }
                float rr  = in ? 1.0f / s : 0.f;
                float acc = 0.f;
                #pragma unroll
                for (int t = 0; t < 8; ++t) { wt[t] *= rr; acc += wt[t]; }

                union { float4 f4; __half2 h[4]; } u;
                u.h[0] = __floats2half2_rn(wt[0], wt[1]);
                u.h[1] = __floats2half2_rn(wt[2], wt[3]);
                u.h[2] = __floats2half2_rn(wt[4], wt[5]);
                u.h[3] = __floats2half2_rn(wt[6], wt[7]);
                wv[r][k][0] = u.h[0]; wv[r][k][1] = u.h[1];
                wv[r][k][2] = u.h[2]; wv[r][k][3] = u.h[3];
                wcc[r][k] = in ? 1.0f - acc : 0.f;

                if (MODE == 0) {
                    // store interior weights for launch 2 (each image px
                    // interior to exactly one block; rows/cols unique/thread)
                    if ((unsigned)(gy - oy) < (unsigned)TILE &&
                        (unsigned)(gx - ox) < (unsigned)TILE) {
                        *(float4*)(wA + 4 * idx) = u.f4;
                        wC[idx] = wcc[r][k];
                    }
                }
            }
        }
    }
    __syncthreads();

    // ---- 12 fused steps; 4x8 window via 8x ds_read_b128, aligned b64 writes
    const float* fin = fA;
    float*       fo  = fB;

    #pragma unroll 1
    for (int s = 0; s < TSTEPS; ++s) {
        // wave-uniform liveness: wave w writes staged rows 8w+1..8w+8; row
        // ring needed after step s is [s+1, 64-s]
        const bool live = (8 * w + 8 >= s + 1) && (8 * w + 1 <= 64 - s);
        if (live) {
            // window staged rows 2R..2R+3, staged dword cols 4cu..4cu+7
            const float* bp = fin + (2 * R) * PITCH + 4 * cu;
            float4 A0 = *(const float4*)(bp);
            float4 A1 = *(const float4*)(bp + 4);
            float4 B0 = *(const float4*)(bp + PITCH);
            float4 B1 = *(const float4*)(bp + PITCH + 4);
            float4 C0 = *(const float4*)(bp + 2 * PITCH);
            float4 C1 = *(const float4*)(bp + 2 * PITCH + 4);
            float4 D0 = *(const float4*)(bp + 3 * PITCH);
            float4 D1 = *(const float4*)(bp + 3 * PITCH + 4);
            float a[8] = {A0.x, A0.y, A0.z, A0.w, A1.x, A1.y, A1.z, A1.w};
            float bb[8] = {B0.x, B0.y, B0.z, B0.w, B1.x, B1.y, B1.z, B1.w};
            float cc[8] = {C0.x, C0.y, C0.z, C0.w, C1.x, C1.y, C1.z, C1.w};
            float dd[8] = {D0.x, D0.y, D0.z, D0.w, D1.x, D1.y, D1.z, D1.w};

            // outputs: weight rows 2R,2R+1 = staged rows 2R+1,2R+2;
            // weight col 4cu+k = staged col 4cu+2+k; window idx k+1..k+3
            float o0[4], o1[4];
            #pragma unroll
            for (int k = 0; k < 4; ++k) {
                o0[k] = wcc[0][k] * bb[k + 2]
                    + __low2float (wv[0][k][0]) * a [k + 1]   // NW
                    + __high2float(wv[0][k][0]) * a [k + 2]   // N
                    + __low2float (wv[0][k][1]) * a [k + 3]   // NE
                    + __high2float(wv[0][k][1]) * bb[k + 1]   // W
                    + __low2float (wv[0][k][2]) * bb[k + 3]   // E
                    + __high2float(wv[0][k][2]) * cc[k + 1]   // SW
                    + __low2float (wv[0][k][3]) * cc[k + 2]   // S
                    + __high2float(wv[0][k][3]) * cc[k + 3];  // SE
                o1[k] = wcc[1][k] * cc[k + 2]
                    + __low2float (wv[1][k][0]) * bb[k + 1]
                    + __high2float(wv[1][k][0]) * bb[k + 2]
                    + __low2float (wv[1][k][1]) * bb[k + 3]
                    + __high2float(wv[1][k][1]) * cc[k + 1]
                    + __low2float (wv[1][k][2]) * cc[k + 3]
                    + __high2float(wv[1][k][2]) * dd[k + 1]
                    + __low2float (wv[1][k][3]) * dd[k + 2]
                    + __high2float(wv[1][k][3]) * dd[k + 3];
            }
            float* wp = fo + (2 * R + 1) * PITCH + 4 * cu + 2;   // 8B aligned
            *(float2*)(wp)             = make_float2(o0[0], o0[1]);
            *(float2*)(wp + 2)         = make_float2(o0[2], o0[3]);
            *(float2*)(wp + PITCH)     = make_float2(o1[0], o1[1]);
            *(float2*)(wp + PITCH + 2) = make_float2(o1[2], o1[3]);
        }
        __syncthreads();
        const float* t = fin; fin = fo; fo = (float*)t;
    }

    // ---- store 40x40 tile (fin == fA after 12 steps);
    //      gy = oy+r -> staged row 13+r; gx = ox+c -> staged col 14+c
    for (int i = tid; i < TILE * (TILE / 4); i += NT) {
        int r  = i / (TILE / 4);
        int c4 = (i - r * (TILE / 4)) * 4;
        const float* p = fin + (IH + r) * PITCH + (IH + 1) + c4;
        float4 v = make_float4(p[0], p[1], p[2], p[3]);
        *(float4*)&db[(size_t)(oy + r) * WIMG + ox + c4] = v;
    }
}

extern "C" void kernel_launch(void* const* d_in, const int* in_sizes, int n_in,
                              void* d_out, int out_size, void* d_ws, size_t ws_size,
                              hipStream_t stream)
{
    const float* aff  = (const float*)d_in[0];
    const float* feat = (const float*)d_in[1];
    float* out = (float*)d_out;

    char* ws = (char*)d_ws;
    float*   wsFrame = (float*)ws;
    __half2* wA      = (__half2*)(ws + WS_FRAME_B);
    float*   wC      = (float*)(ws + WS_FRAME_B + WS_WA_B);

    dim3 blk(NT, 1, 1);
    dim3 grd(WIMG / TILE, HIMG / TILE, BN);   // 16 x 12 x 8 = 1536 blocks

    if (ws_size >= WS_NEED) {
        affprop12<0><<<grd, blk, 0, stream>>>(aff, wA, wC, feat, wsFrame);
        affprop12<1><<<grd, blk, 0, stream>>>(aff, wA, wC, wsFrame, out);
    } else {
        affprop12<2><<<grd, blk, 0, stream>>>(aff, nullptr, nullptr, feat, wsFrame);
        affprop12<2><<<grd, blk, 0, stream>>>(aff, nullptr, nullptr, wsFrame, out);
    }
}

// Round 7
// 229.322 us; speedup vs baseline: 2.2390x; 1.2869x over previous
//
#include <hip/hip_runtime.h>
#include <hip/hip_fp16.h>
#include <cstddef>

// AffinityPropagate: per-pixel normalized 3x3 stencil, 24 steps.
// R12 = R9 skeleton (1col x 8rows/thread, b32 stride-1 LDS = the ONLY
// conflict-free pattern measured: 0.39M vs 5.8M (float2, R8) / 23.4M
// (float4, R10/R11) conflict cycles) with two LDS-instruction cuts:
//  (a) register-carried center column: thread's 10 center reads shrink to 2
//      (rows 8g / 8g+9 from neighbor waves); own rows 8g+1..8g+8 are last
//      step's outputs, kept in oc[8]. Coherent because wave liveness is
//      monotone and live waves write every step; step 0 seeds oc from fA.
//  (b) side cols c and c+2 are 2 dwords apart -> ds_read2_b32
//      offset0:k offset1:k+2 pairs each row's two side reads.
// Per wave-step: ~28 LDS insts -> ~20 (10 read2 + 2 b32 + 8 write_b32),
// width unchanged. Modeled LDS pipe 174 -> 128 cy/wave-step.
// R10/R11 lesson (hard constraint): per-lane LDS vectors wider than b32
// create real conflicts on this access pattern regardless of alignment.
//
// Tap order: w0=NW w1=N w2=NE w3=W [center] w4=E w5=SW w6=S w7=SE
//
// Ring/frontier: staged halo 13 (66x66), weight halo 12 (64x64 = staged rows/
// cols 1..64, rewritten every step). Valid staged rings after step s: [s,65-s];
// after 12 steps rows/cols 12..53 valid; output tile is 13..52. Out-of-image
// px have all-zero weights -> stay exactly 0 = zero padding.

#define HIMG 480
#define WIMG 640
#define HW   (HIMG * WIMG)
#define BN   8

#define TILE   40
#define TSTEPS 12
#define IH     13                // staged halo
#define WHL    12                // weight halo
#define SW     66                // staged rows/cols
#define PITCH  68                // LDS row pitch (floats)
#define NT     512

#define WS_FRAME_B  ((size_t)BN * HW * 4)            // 9,830,400
#define WS_WA_B     ((size_t)BN * HW * 16)           // 39,321,600
#define WS_WC_B     ((size_t)BN * HW * 4)            // 9,830,400
#define WS_NEED     (WS_FRAME_B + WS_WA_B + WS_WC_B) // 58,982,400

// MODE: 0 = normalize in-kernel + store interior weights to wA/wC
//       1 = load packed weights from wA/wC
//       2 = normalize in-kernel, no store (fallback when ws too small)
template <int MODE>
__global__ __launch_bounds__(NT, 3) void affprop12(
    const float* __restrict__ aff,
    __half2* __restrict__ wA,
    float* __restrict__ wC,
    const float* __restrict__ src,
    float* __restrict__ dst)
{
    __shared__ float fA[SW * PITCH];
    __shared__ float fB[SW * PITCH];

    const int tid = threadIdx.x;
    const int ox  = blockIdx.x * TILE;
    const int oy  = blockIdx.y * TILE;
    const int b   = blockIdx.z;

    const float* __restrict__ sb = src + (size_t)b * HW;
    float*       __restrict__ db = dst + (size_t)b * HW;

    // ---- stage input region [oy-13, oy+53) x [ox-13, ox+53), 0 outside image
    for (int i = tid; i < SW * SW; i += NT) {
        int r  = i / SW;
        int c  = i - r * SW;
        int gy = oy - IH + r;
        int gx = ox - IH + c;
        float v = 0.f;
        if ((unsigned)gy < (unsigned)HIMG && (unsigned)gx < (unsigned)WIMG)
            v = sb[gy * WIMG + gx];
        fA[r * PITCH + c] = v;
    }
    // ---- zero-fill buffer B (deterministic stale rings)
    for (int i = tid; i < SW * PITCH / 4; i += NT)
        *(float4*)&fB[4 * i] = make_float4(0.f, 0.f, 0.f, 0.f);

    // ---- per-thread: weight column c, row group g (8 rows)
    const int c  = tid & 63;          // weight col 0..63
    const int g  = tid >> 6;          // row group 0..7
    const int sc = c + 1;             // staged col of this thread's outputs

    float ww[8][8];     // [row i][tap 0..7] (compiler repacks to half2+fma_mix)
    float wcc[8];       // center weights

    #pragma unroll
    for (int i = 0; i < 8; ++i) {
        const int gy = oy - WHL + 8 * g + i;
        const int gx = ox - WHL + c;
        const bool in = (unsigned)gy < (unsigned)HIMG && (unsigned)gx < (unsigned)WIMG;
        const size_t idx = (size_t)b * HW + (size_t)gy * WIMG + gx;

        if (MODE == 1) {
            if (in) {
                union { float4 f4; __half2 h[4]; } u;
                u.f4 = *(const float4*)(wA + 4 * idx);
                #pragma unroll
                for (int t = 0; t < 4; ++t) {
                    ww[i][2 * t]     = __low2float (u.h[t]);
                    ww[i][2 * t + 1] = __high2float(u.h[t]);
                }
                wcc[i] = wC[idx];
            } else {
                #pragma unroll
                for (int t = 0; t < 8; ++t) ww[i][t] = 0.f;
                wcc[i] = 0.f;
            }
        } else {
            float w[8];
            float s = 0.f;
            if (in) {
                const float* ap = aff + (size_t)b * 8 * HW + (size_t)gy * WIMG + gx;
                #pragma unroll
                for (int k = 0; k < 8; ++k) { w[k] = ap[(size_t)k * HW]; s += fabsf(w[k]); }
            } else {
                #pragma unroll
                for (int k = 0; k < 8; ++k) w[k] = 0.f;
                s = 1.f;
            }
            float rr  = in ? 1.0f / s : 0.f;
            float acc = 0.f;
            #pragma unroll
            for (int k = 0; k < 8; ++k) { w[k] *= rr; acc += w[k]; }

            #pragma unroll
            for (int k = 0; k < 8; ++k) ww[i][k] = w[k];
            wcc[i] = in ? 1.0f - acc : 0.f;

            if (MODE == 0) {
                // store interior weights for launch 2 (each image px interior
                // to exactly one block); pack to half2 for storage only
                if ((unsigned)(gy - oy) < (unsigned)TILE &&
                    (unsigned)(gx - ox) < (unsigned)TILE) {
                    union { float4 f4; __half2 h[4]; } u;
                    u.h[0] = __floats2half2_rn(w[0], w[1]);
                    u.h[1] = __floats2half2_rn(w[2], w[3]);
                    u.h[2] = __floats2half2_rn(w[4], w[5]);
                    u.h[3] = __floats2half2_rn(w[6], w[7]);
                    *(float4*)(wA + 4 * idx) = u.f4;
                    wC[idx] = wcc[i];
                }
            }
        }
    }
    __syncthreads();

    // ---- seed register center column from staged fA (rows 8g+1..8g+8, col sc)
    float oc[8];
    {
        const float* cp = fA + (8 * g + 1) * PITCH + sc;
        #pragma unroll
        for (int i = 0; i < 8; ++i) oc[i] = cp[i * PITCH];
    }

    // ---- 12 fused steps; sides via paired b32 reads, center carried in regs
    const float* fin = fA;
    float*       fo  = fB;

    #pragma unroll 1
    for (int s = 0; s < TSTEPS; ++s) {
        // wave-uniform liveness: wave g writes staged rows 8g+1..8g+8; the
        // ring needed after step s is [s+1, 64-s].
        const bool live = (8 * g + 8 >= s + 1) && (8 * g + 1 <= 64 - s);
        if (live) {
            const float* bp = fin + (8 * g) * PITCH + c;   // staged cols sc-1..sc+1
            float s0[10], s2[10];
            #pragma unroll
            for (int r = 0; r < 10; ++r) {
                s0[r] = bp[r * PITCH];        // col sc-1  } one ds_read2_b32
                s2[r] = bp[r * PITCH + 2];    // col sc+1  } offset0:k offset1:k+2
            }
            float t1[10];
            t1[0] = bp[1];                    // row 8g center (wave g-1's row)
            #pragma unroll
            for (int i = 0; i < 8; ++i) t1[i + 1] = oc[i];
            t1[9] = bp[9 * PITCH + 1];        // row 8g+9 center (wave g+1's row)

            float* wp = fo + (8 * g + 1) * PITCH + sc;
            #pragma unroll
            for (int i = 0; i < 8; ++i) {
                float o = wcc[i]   * t1[i + 1]
                        + ww[i][0] * s0[i]        // NW
                        + ww[i][1] * t1[i]        // N
                        + ww[i][2] * s2[i]        // NE
                        + ww[i][3] * s0[i + 1]    // W
                        + ww[i][4] * s2[i + 1]    // E
                        + ww[i][5] * s0[i + 2]    // SW
                        + ww[i][6] * t1[i + 2]    // S
                        + ww[i][7] * s2[i + 2];   // SE
                wp[i * PITCH] = o;
                oc[i] = o;
            }
        }
        __syncthreads();
        const float* t = fin; fin = fo; fo = (float*)t;
    }

    // ---- store 40x40 tile (fin == fA after 12 steps)
    for (int i = tid; i < TILE * (TILE / 4); i += NT) {
        int r  = i / (TILE / 4);
        int c4 = (i - r * (TILE / 4)) * 4;
        const float* p = fin + (IH + r) * PITCH + IH + c4;
        float4 v = make_float4(p[0], p[1], p[2], p[3]);
        *(float4*)&db[(size_t)(oy + r) * WIMG + ox + c4] = v;
    }
}

extern "C" void kernel_launch(void* const* d_in, const int* in_sizes, int n_in,
                              void* d_out, int out_size, void* d_ws, size_t ws_size,
                              hipStream_t stream)
{
    const float* aff  = (const float*)d_in[0];
    const float* feat = (const float*)d_in[1];
    float* out = (float*)d_out;

    char* ws = (char*)d_ws;
    float*   wsFrame = (float*)ws;
    __half2* wA      = (__half2*)(ws + WS_FRAME_B);
    float*   wC      = (float*)(ws + WS_FRAME_B + WS_WA_B);

    dim3 blk(NT, 1, 1);
    dim3 grd(WIMG / TILE, HIMG / TILE, BN);   // 16 x 12 x 8 = 1536 blocks

    if (ws_size >= WS_NEED) {
        affprop12<0><<<grd, blk, 0, stream>>>(aff, wA, wC, feat, wsFrame);
        affprop12<1><<<grd, blk, 0, stream>>>(aff, wA, wC, wsFrame, out);
    } else {
        affprop12<2><<<grd, blk, 0, stream>>>(aff, nullptr, nullptr, feat, wsFrame);
        affprop12<2><<<grd, blk, 0, stream>>>(aff, nullptr, nullptr, wsFrame, out);
    }
}